// Round 2
// baseline (573.582 us; speedup 1.0000x reference)
//
#include <hip/hip_runtime.h>
#include <math.h>

// Problem constants
#define B_    64
#define MAXT  511
#define TP1   512
#define S_    1024
#define H_    4096
#define M_TOTAL (B_*TP1)   // 32768 rows
#define NT    (S_/64)      // 16 K-tiles of BK=64

typedef __attribute__((ext_vector_type(8))) short  short8;   // 8 bf16 (MFMA A/B frag)
typedef __attribute__((ext_vector_type(4))) float  float4v;  // MFMA C/D frag

// ---- workspace layout (bytes) ----
#define ZBUF_BYTES ((size_t)M_TOTAL*4*sizeof(float))   // 524288
#define SBF_OFF    0x81000                             // 528384 >= ZBUF_BYTES
#define SBF_BYTES  ((size_t)M_TOTAL*S_*2)
#define W1T_OFF    (SBF_OFF + SBF_BYTES)

static __device__ __forceinline__ unsigned short f2bf(float f) {
    unsigned int u = __float_as_uint(f);
    u = u + 0x7fffu + ((u >> 16) & 1u);   // round-to-nearest-even
    return (unsigned short)(u >> 16);
}

// ---- merged pre-pass (unchanged from 471us baseline) ----
__global__ __launch_bounds__(256) void prep_kernel(const float* __restrict__ s,
                                                   const float* __restrict__ W1,
                                                   const int*   __restrict__ lengths,
                                                   unsigned short* __restrict__ Sb,
                                                   unsigned short* __restrict__ W1T) {
    int bid = blockIdx.x;
    if (bid < 16384) {
        int row = 2 * bid + (threadIdx.x >> 7);
        int b = row >> 9, t = row & 511;
        if (t >= lengths[b]) return;
        size_t idx = (size_t)row * S_ + (threadIdx.x & 127) * 8;
        float4v f0 = __builtin_nontemporal_load((const float4v*)(s + idx));
        float4v f1 = __builtin_nontemporal_load((const float4v*)(s + idx + 4));
        short8 o;
        o[0] = (short)f2bf(f0[0]); o[1] = (short)f2bf(f0[1]);
        o[2] = (short)f2bf(f0[2]); o[3] = (short)f2bf(f0[3]);
        o[4] = (short)f2bf(f1[0]); o[5] = (short)f2bf(f1[1]);
        o[6] = (short)f2bf(f1[2]); o[7] = (short)f2bf(f1[3]);
        *(short8*)(Sb + idx) = o;
    } else {
        __shared__ float tile[32][33];
        int tb = bid - 16384;
        int h0 = (tb & 127) * 32;
        int k0 = (tb >> 7) * 32;
        int tx = threadIdx.x & 31, ty = threadIdx.x >> 5;
        for (int r = ty; r < 32; r += 8)
            tile[r][tx] = __builtin_nontemporal_load(&W1[(size_t)(k0 + r) * H_ + h0 + tx]);
        __syncthreads();
        for (int r = ty; r < 32; r += 8)
            W1T[(size_t)(h0 + r) * S_ + k0 + tx] = f2bf(tile[tx][r]);
    }
}

// ---- main fused GEMM: 256x256 tile, BK=64, 8-phase counted-vmcnt schedule ----
// 512 threads = 8 waves (2M x 4N), per-wave 128x64 C-tile, 128 KiB LDS dbuf.
// Staging: global_load_lds width-16 (linear LDS dest, wave-uniform base) with
// inverse-swizzled per-lane global source; fragment ds_read_b128 applies the
// same 3-bit XOR swizzle (byte ^= ((row&7)<<4)) -> balanced 8-lanes-per-slot,
// conflict-free for wave64 ds_read_b128.
// Region schedule per K-tile t (phases = C-quadrants of the wave tile):
//   ph1: read A-mh0(8)+B-nf01(4); stage (t+1).A0 -> buf^1 ; MFMA (mh0,nh0)
//   ph2: read B-nf23(4);          stage (t+1).A1 -> buf^1 ; MFMA (mh0,nh1)
//   ph3: read A-mh1(8);           stage (t+2).B0 -> buf   ; MFMA (mh1,nh1)
//   ph4:                          stage (t+2).B1 -> buf   ; MFMA (mh1,nh0); vmcnt(4)
// vmcnt ledger (steady state, end of iter t): queue = [B(t+1)x4, A(t+1)x4,
// B(t+2)x4]; vmcnt(4) retires the 8 oldest = tile t+1 fully resident before
// the barrier into iter t+1. B regions of tile t retire (reads done) at ph2,
// A regions at ph3 -> the stages above never overwrite live data.
typedef __attribute__((address_space(1))) unsigned int gu32;
typedef __attribute__((address_space(3))) unsigned int lu32;
static __device__ __forceinline__ void gload16(const void* g, void* l) {
    __builtin_amdgcn_global_load_lds((gu32*)g, (lu32*)l, 16, 0, 0);
}
static __device__ __forceinline__ short8 ld8(const char* p) { return *(const short8*)p; }

__global__ __launch_bounds__(512, 2) void gemm_fused_kernel(
        const unsigned short* __restrict__ Sb,    // M x S bf16
        const unsigned short* __restrict__ W1T,   // H x S bf16
        const float* __restrict__ b1,             // H
        const float* __restrict__ W2,             // H x 32 fp32 (cols 0..3 used)
        const int*   __restrict__ lengths,        // B
        float*       __restrict__ zbuf)           // M x 4
{
    // XCD-swizzled 1D grid: 2048 blocks; xcd owns 2 n-panels (1 MB W1T, L2-resident)
    int id  = blockIdx.x;
    int xcd = id & 7;
    int sl  = id >> 3;                 // 0..255
    int ntile = xcd * 2 + (sl >> 7);   // 0..15
    int mtile = sl & 127;              // 0..127
    int bi = mtile >> 1;
    if (lengths[bi] <= (mtile & 1) * 256) return;   // whole 256-row tile dead (uniform)
    int m0 = mtile * 256;
    int n0 = ntile * 256;

    __shared__ unsigned short lds[2][2][16384];   // [buf][A|B][32 KB] = 128 KiB
    char* L = (char*)lds;

    int tid = threadIdx.x;
    int wid = tid >> 6, lane = tid & 63;
    int lane15 = lane & 15, quad = lane >> 4;
    int wave_m = (wid >> 2) * 128;     // 0 / 128
    int wave_n = (wid & 3) * 64;       // 0 / 64 / 128 / 192

    // fragment-read addressing (rows of 128 B = BK*2; swizzle bits 4..6)
    int smask = (lane15 & 7) << 4;
    int c0 = (quad * 16) ^ smask;          // k-chunk byte for kk=0
    int c1 = (64 + quad * 16) ^ smask;     // kk=1
    int aRow = (wave_m + lane15) * 128;
    int bRow = (wave_n + lane15) * 128;

    // staging: per-thread inverse-swizzled global source; linear LDS dest
    int srow = tid >> 3;                                    // 0..63
    int scol = ((tid & 7) * 16) ^ ((srow & 7) << 4);
    const char* gAs = (const char*)Sb  + (size_t)(m0 + srow) * 2048 + scol;
    const char* gBs = (const char*)W1T + (size_t)(n0 + srow) * 2048 + scol;
    char* dA = L + wid * 1024;             // + bb*65536 + h*16384 (+8192 for issue 1)
    char* dB = L + 32768 + wid * 1024;

#define STAGE_A(bb,h,tt) do { \
    const char* g_ = gAs + (h)*262144 + (tt)*128; \
    char* d_ = dA + (bb)*65536 + (h)*16384; \
    gload16(g_, d_); gload16(g_ + 131072, d_ + 8192); } while(0)
#define STAGE_B(bb,h,tt) do { \
    const char* g_ = gBs + (h)*262144 + (tt)*128; \
    char* d_ = dB + (bb)*65536 + (h)*16384; \
    gload16(g_, d_); gload16(g_ + 131072, d_ + 8192); } while(0)

    float4v acc[8][4] = {};
    short8 af[4][2], bfr[4][2];

    // prologue: tile0 {B0,B1,A0,A1} + tile1 {B0,B1} = 12 loads; wait oldest 8
    STAGE_B(0,0,0); STAGE_B(0,1,0); STAGE_A(0,0,0); STAGE_A(0,1,0);
    STAGE_B(1,0,1); STAGE_B(1,1,1);
    asm volatile("s_waitcnt vmcnt(4)" ::: "memory");
    __builtin_amdgcn_sched_barrier(0);
    __builtin_amdgcn_s_barrier();

#define MFMA16(MH, NF0) \
    _Pragma("unroll") for (int mf = 0; mf < 4; ++mf) \
    _Pragma("unroll") for (int nf = 0; nf < 2; ++nf) \
    _Pragma("unroll") for (int kk = 0; kk < 2; ++kk) \
        acc[(MH)*4+mf][(NF0)+nf] = __builtin_amdgcn_mfma_f32_16x16x32_bf16( \
            af[mf][kk], bfr[(NF0)+nf][kk], acc[(MH)*4+mf][(NF0)+nf], 0, 0, 0)

#define PH_BEGIN() \
    __builtin_amdgcn_s_barrier(); \
    asm volatile("s_waitcnt lgkmcnt(0)" ::: "memory"); \
    __builtin_amdgcn_sched_barrier(0); \
    __builtin_amdgcn_s_setprio(1)
#define PH_END() \
    __builtin_amdgcn_s_setprio(0); \
    __builtin_amdgcn_sched_barrier(0); \
    __builtin_amdgcn_s_barrier()

#pragma unroll 2
    for (int t = 0; t < NT; ++t) {
        int bb = t & 1;
        const char* A  = L + bb * 65536;
        const char* Bm = A + 32768;
        // ---- phase 1: (mh0, nh0) -- 12 ds_read_b128 ----
#pragma unroll
        for (int mf = 0; mf < 4; ++mf) {
            af[mf][0] = ld8(A + aRow + mf*2048 + c0);
            af[mf][1] = ld8(A + aRow + mf*2048 + c1);
        }
#pragma unroll
        for (int nf = 0; nf < 2; ++nf) {
            bfr[nf][0] = ld8(Bm + bRow + nf*2048 + c0);
            bfr[nf][1] = ld8(Bm + bRow + nf*2048 + c1);
        }
        if (t + 1 < NT) STAGE_A(bb^1, 0, t+1);
        PH_BEGIN();
        MFMA16(0, 0);
        PH_END();
        // ---- phase 2: (mh0, nh1) -- 4 ds_read_b128 ----
#pragma unroll
        for (int nf = 2; nf < 4; ++nf) {
            bfr[nf][0] = ld8(Bm + bRow + nf*2048 + c0);
            bfr[nf][1] = ld8(Bm + bRow + nf*2048 + c1);
        }
        if (t + 1 < NT) STAGE_A(bb^1, 1, t+1);
        PH_BEGIN();
        MFMA16(0, 2);
        PH_END();
        // ---- phase 3: (mh1, nh1) -- 8 ds_read_b128 ----
#pragma unroll
        for (int mf = 0; mf < 4; ++mf) {
            af[mf][0] = ld8(A + aRow + 8192 + mf*2048 + c0);
            af[mf][1] = ld8(A + aRow + 8192 + mf*2048 + c1);
        }
        if (t + 2 < NT) STAGE_B(bb, 0, t+2);
        PH_BEGIN();
        MFMA16(1, 2);
        PH_END();
        // ---- phase 4: (mh1, nh0) -- no ds_read; counted vmcnt, never 0 mid-loop ----
        if (t + 2 < NT) STAGE_B(bb, 1, t+2);
        __builtin_amdgcn_s_barrier();
        __builtin_amdgcn_sched_barrier(0);
        __builtin_amdgcn_s_setprio(1);
        MFMA16(1, 0);
        __builtin_amdgcn_s_setprio(0);
        __builtin_amdgcn_sched_barrier(0);
        if (t < NT - 2)       { asm volatile("s_waitcnt vmcnt(4)" ::: "memory"); __builtin_amdgcn_sched_barrier(0); }
        else if (t == NT - 2) { asm volatile("s_waitcnt vmcnt(0)" ::: "memory"); __builtin_amdgcn_sched_barrier(0); }
        __builtin_amdgcn_s_barrier();
    }

    // ---- fused epilogue: relu(h) @ W2[:,0:4], shuffle-reduce, atomicAdd ----
    float4v w2r[4];
    float   b1v[4];
#pragma unroll
    for (int nf = 0; nf < 4; ++nf) {
        int n_g = n0 + wave_n + nf * 16 + lane15;
        w2r[nf] = *(const float4v*)(W2 + (size_t)n_g * 32);
        b1v[nf] = b1[n_g];
    }
#pragma unroll
    for (int ms = 0; ms < 8; ++ms) {
        float p[4][4];
#pragma unroll
        for (int r = 0; r < 4; ++r)
#pragma unroll
            for (int c = 0; c < 4; ++c) p[r][c] = 0.f;
#pragma unroll
        for (int nf = 0; nf < 4; ++nf) {
            float4v av = acc[ms][nf];
#pragma unroll
            for (int r = 0; r < 4; ++r) {
                float h = av[r] + b1v[nf];
                h = h > 0.f ? h : 0.f;
                p[r][0] += h * w2r[nf][0];
                p[r][1] += h * w2r[nf][1];
                p[r][2] += h * w2r[nf][2];
                p[r][3] += h * w2r[nf][3];
            }
        }
#pragma unroll
        for (int off = 1; off < 16; off <<= 1)
#pragma unroll
            for (int r = 0; r < 4; ++r)
#pragma unroll
                for (int c = 0; c < 4; ++c)
                    p[r][c] += __shfl_xor(p[r][c], off);
        if (lane15 < 4) {
            int c = lane15;
#pragma unroll
            for (int r = 0; r < 4; ++r) {
                int mg = m0 + wave_m + ms * 16 + quad * 4 + r;
                atomicAdd(&zbuf[(size_t)mg * 4 + c], p[r][c]);
            }
        }
    }
#undef STAGE_A
#undef STAGE_B
#undef MFMA16
#undef PH_BEGIN
#undef PH_END
}

// ---- log-softmax gather + masked sum (unchanged) ----
__global__ __launch_bounds__(128) void reduce_logp_kernel(
        const float* __restrict__ zbuf,
        const int*   __restrict__ actions,
        const int*   __restrict__ lengths,
        const float* __restrict__ b2,
        float*       __restrict__ out)
{
    int b = blockIdx.x;
    int t = blockIdx.y * 128 + threadIdx.x;
    int len = lengths[b];
    float local = 0.f;
    if (t < MAXT && t < len) {
        int row = b * TP1 + t;
        float4v z = *(const float4v*)(zbuf + (size_t)row * 4);
        float z0 = z[0] + b2[0], z1 = z[1] + b2[1], z2 = z[2] + b2[2], z3 = z[3] + b2[3];
        float mx = fmaxf(fmaxf(z0, z1), fmaxf(z2, z3));
        float se = expf(z0 - mx) + expf(z1 - mx) + expf(z2 - mx) + expf(z3 - mx);
        int a = actions[b * MAXT + t];
        float za = (a == 0) ? z0 : (a == 1) ? z1 : (a == 2) ? z2 : z3;
        local = (za - mx) - logf(se);
    }
#pragma unroll
    for (int off = 32; off > 0; off >>= 1) local += __shfl_xor(local, off);
    __shared__ float wsum[2];
    if ((threadIdx.x & 63) == 0) wsum[threadIdx.x >> 6] = local;
    __syncthreads();
    if (threadIdx.x == 0) atomicAdd(out, -(wsum[0] + wsum[1]));
}

extern "C" void kernel_launch(void* const* d_in, const int* in_sizes, int n_in,
                              void* d_out, int out_size, void* d_ws, size_t ws_size,
                              hipStream_t stream) {
    const float* s       = (const float*)d_in[0];  // (64,512,1024) fp32
    const int*   actions = (const int*)  d_in[1];  // (64,511)
    const int*   lengths = (const int*)  d_in[2];  // (64,)
    const float* W1      = (const float*)d_in[3];  // (1024,4096)
    const float* b1      = (const float*)d_in[4];  // (4096,)
    const float* W2      = (const float*)d_in[5];  // (4096,32)
    const float* b2      = (const float*)d_in[6];  // (32,)

    char* ws = (char*)d_ws;
    float*          zbuf = (float*)ws;             // [0, 512KB)
    unsigned short* Sb   = (unsigned short*)(ws + SBF_OFF);
    unsigned short* W1T  = (unsigned short*)(ws + W1T_OFF);

    hipMemsetAsync(ws, 0, ZBUF_BYTES, stream);
    hipMemsetAsync(d_out, 0, sizeof(float), stream);

    // merged pre-pass: s->bf16 (live rows, nt loads) + W1->W1T bf16
    prep_kernel<<<dim3(16384 + 4096), 256, 0, stream>>>(s, W1, lengths, Sb, W1T);
    // 256x256 8-phase fused GEMM + relu + W2[:,0:4] projection
    gemm_fused_kernel<<<dim3(2048), 512, 0, stream>>>(Sb, W1T, b1, W2, lengths, zbuf);
    // log-softmax gather + masked sum -> d_out
    reduce_logp_kernel<<<dim3(B_, 4), 128, 0, stream>>>(zbuf, actions, lengths, b2, (float*)d_out);
}